// Round 6
// baseline (913.202 us; speedup 1.0000x reference)
//
#include <hip/hip_runtime.h>
#include <hip/hip_bf16.h>
#include <math.h>

#define L_SEQ   1024
#define DMODEL  1024
#define DINNER  2048
#define DSTATE  16
#define DTRANK  64
#define NXP     96      // DTRANK + 2*DSTATE
#define LN_EPS  1e-5f
#define CHUNK   16
#define NCHUNK  (L_SEQ / CHUNK)      // 64
#define SK(l)   ((l) + ((l) >> 5))   // LDS skew: kills 4-way bank conflict

typedef __bf16 bf16x8 __attribute__((ext_vector_type(8)));
typedef float  f32x4  __attribute__((ext_vector_type(4)));

// ---------------------------------------------------------------------------
// bf16 MFMA GEMM (m97 structure): C[M,N] = A[M,K] @ W[N,K]^T, fp32 out.
// ---------------------------------------------------------------------------
__global__ __launch_bounds__(256)
void gemm_bt_bf16(const __hip_bfloat16* __restrict__ A,
                  const __hip_bfloat16* __restrict__ W,
                  float* __restrict__ C,
                  int K, int lda, int ldb, int ldc) {
    __shared__ __hip_bfloat16 As[128][32];
    __shared__ __hip_bfloat16 Bs[128][32];
    const int tid  = threadIdx.x;
    const int lane = tid & 63;
    const int wave = tid >> 6;
    const int m0 = blockIdx.y * 128, n0 = blockIdx.x * 128;
    const int wm = (wave >> 1) * 64, wn = (wave & 1) * 64;
    const int srow = tid >> 2, skcol = (tid & 3) << 3;
    const int fm = lane & 15, fk = (lane >> 4) << 3;

    f32x4 acc[4][4] = {};

    const __hip_bfloat16* Ap0 = A + (size_t)(m0 + srow) * lda + skcol;
    const __hip_bfloat16* Ap1 = Ap0 + (size_t)64 * lda;
    const __hip_bfloat16* Wp0 = W + (size_t)(n0 + srow) * ldb + skcol;
    const __hip_bfloat16* Wp1 = Wp0 + (size_t)64 * ldb;

    for (int k0 = 0; k0 < K; k0 += 32) {
        __syncthreads();
        __builtin_amdgcn_global_load_lds(
            (const __attribute__((address_space(1))) unsigned int*)(Ap0 + k0),
            (__attribute__((address_space(3))) unsigned int*)&As[srow][skcol], 16, 0, 0);
        __builtin_amdgcn_global_load_lds(
            (const __attribute__((address_space(1))) unsigned int*)(Ap1 + k0),
            (__attribute__((address_space(3))) unsigned int*)&As[64 + srow][skcol], 16, 0, 0);
        __builtin_amdgcn_global_load_lds(
            (const __attribute__((address_space(1))) unsigned int*)(Wp0 + k0),
            (__attribute__((address_space(3))) unsigned int*)&Bs[srow][skcol], 16, 0, 0);
        __builtin_amdgcn_global_load_lds(
            (const __attribute__((address_space(1))) unsigned int*)(Wp1 + k0),
            (__attribute__((address_space(3))) unsigned int*)&Bs[64 + srow][skcol], 16, 0, 0);
        __syncthreads();

        bf16x8 af[4], bfr[4];
        #pragma unroll
        for (int i = 0; i < 4; ++i) {
            af[i]  = *(const bf16x8*)&As[wm + i * 16 + fm][fk];
            bfr[i] = *(const bf16x8*)&Bs[wn + i * 16 + fm][fk];
        }
        #pragma unroll
        for (int mt = 0; mt < 4; ++mt)
            #pragma unroll
            for (int nt = 0; nt < 4; ++nt)
                acc[mt][nt] = __builtin_amdgcn_mfma_f32_16x16x32_bf16(
                    af[mt], bfr[nt], acc[mt][nt], 0, 0, 0);
    }

    const int crow = (lane >> 4) << 2;
    const int ccol = lane & 15;
    #pragma unroll
    for (int mt = 0; mt < 4; ++mt)
        #pragma unroll
        for (int nt = 0; nt < 4; ++nt) {
            float* cp = C + (size_t)(m0 + wm + mt * 16 + crow) * ldc
                          + n0 + wn + nt * 16 + ccol;
            #pragma unroll
            for (int r = 0; r < 4; ++r) cp[(size_t)r * ldc] = acc[mt][nt][r];
        }
}

// ---------------------------------------------------------------------------
// Split-K variant: grid.z slices K; atomicAdd fp32 epilogue (C zeroed first).
// ---------------------------------------------------------------------------
__global__ __launch_bounds__(256)
void gemm_bt_bf16_sk(const __hip_bfloat16* __restrict__ A,
                     const __hip_bfloat16* __restrict__ W,
                     float* __restrict__ C,
                     int kchunk, int lda, int ldb, int ldc) {
    __shared__ __hip_bfloat16 As[128][32];
    __shared__ __hip_bfloat16 Bs[128][32];
    const int tid  = threadIdx.x;
    const int lane = tid & 63;
    const int wave = tid >> 6;
    const int m0 = blockIdx.y * 128, n0 = blockIdx.x * 128;
    const int k0s = blockIdx.z * kchunk;
    const int wm = (wave >> 1) * 64, wn = (wave & 1) * 64;
    const int srow = tid >> 2, skcol = (tid & 3) << 3;
    const int fm = lane & 15, fk = (lane >> 4) << 3;

    f32x4 acc[4][4] = {};

    const __hip_bfloat16* Ap0 = A + (size_t)(m0 + srow) * lda + skcol;
    const __hip_bfloat16* Ap1 = Ap0 + (size_t)64 * lda;
    const __hip_bfloat16* Wp0 = W + (size_t)(n0 + srow) * ldb + skcol;
    const __hip_bfloat16* Wp1 = Wp0 + (size_t)64 * ldb;

    for (int k0 = k0s; k0 < k0s + kchunk; k0 += 32) {
        __syncthreads();
        __builtin_amdgcn_global_load_lds(
            (const __attribute__((address_space(1))) unsigned int*)(Ap0 + k0),
            (__attribute__((address_space(3))) unsigned int*)&As[srow][skcol], 16, 0, 0);
        __builtin_amdgcn_global_load_lds(
            (const __attribute__((address_space(1))) unsigned int*)(Ap1 + k0),
            (__attribute__((address_space(3))) unsigned int*)&As[64 + srow][skcol], 16, 0, 0);
        __builtin_amdgcn_global_load_lds(
            (const __attribute__((address_space(1))) unsigned int*)(Wp0 + k0),
            (__attribute__((address_space(3))) unsigned int*)&Bs[srow][skcol], 16, 0, 0);
        __builtin_amdgcn_global_load_lds(
            (const __attribute__((address_space(1))) unsigned int*)(Wp1 + k0),
            (__attribute__((address_space(3))) unsigned int*)&Bs[64 + srow][skcol], 16, 0, 0);
        __syncthreads();

        bf16x8 af[4], bfr[4];
        #pragma unroll
        for (int i = 0; i < 4; ++i) {
            af[i]  = *(const bf16x8*)&As[wm + i * 16 + fm][fk];
            bfr[i] = *(const bf16x8*)&Bs[wn + i * 16 + fm][fk];
        }
        #pragma unroll
        for (int mt = 0; mt < 4; ++mt)
            #pragma unroll
            for (int nt = 0; nt < 4; ++nt)
                acc[mt][nt] = __builtin_amdgcn_mfma_f32_16x16x32_bf16(
                    af[mt], bfr[nt], acc[mt][nt], 0, 0, 0);
    }

    const int crow = (lane >> 4) << 2;
    const int ccol = lane & 15;
    #pragma unroll
    for (int mt = 0; mt < 4; ++mt)
        #pragma unroll
        for (int nt = 0; nt < 4; ++nt) {
            float* cp = C + (size_t)(m0 + wm + mt * 16 + crow) * ldc
                          + n0 + wn + nt * 16 + ccol;
            #pragma unroll
            for (int r = 0; r < 4; ++r)
                atomicAdd(&cp[(size_t)r * ldc], acc[mt][nt][r]);
        }
}

// ---------------------------------------------------------------------------
// fp32 tiled GEMM NT (first projection only).
// ---------------------------------------------------------------------------
__global__ __launch_bounds__(256)
void gemm_nt(const float* __restrict__ A, const float* __restrict__ W,
             float* __restrict__ C, int M, int N, int K,
             int lda, int ldb, int ldc) {
    __shared__ float As[16][64];
    __shared__ float Bs[16][64];
    const int tid = threadIdx.x;
    const int tx = tid & 15, ty = tid >> 4;
    const int m0 = blockIdx.y * 64, n0 = blockIdx.x * 64;
    const int lr = tid >> 2;
    const int lk = (tid & 3) << 2;
    float acc[4][4] = {};

    for (int k0 = 0; k0 < K; k0 += 16) {
        float4 av = make_float4(0.f, 0.f, 0.f, 0.f);
        float4 bv = make_float4(0.f, 0.f, 0.f, 0.f);
        const int am = m0 + lr;
        if (am < M) av = *(const float4*)(A + (size_t)am * lda + k0 + lk);
        const int bn = n0 + lr;
        if (bn < N) bv = *(const float4*)(W + (size_t)bn * ldb + k0 + lk);
        __syncthreads();
        As[lk + 0][lr] = av.x; As[lk + 1][lr] = av.y;
        As[lk + 2][lr] = av.z; As[lk + 3][lr] = av.w;
        Bs[lk + 0][lr] = bv.x; Bs[lk + 1][lr] = bv.y;
        Bs[lk + 2][lr] = bv.z; Bs[lk + 3][lr] = bv.w;
        __syncthreads();
        #pragma unroll
        for (int k = 0; k < 16; ++k) {
            const float4 a = *(const float4*)&As[k][ty << 2];
            const float4 b = *(const float4*)&Bs[k][tx << 2];
            acc[0][0] += a.x * b.x; acc[0][1] += a.x * b.y;
            acc[0][2] += a.x * b.z; acc[0][3] += a.x * b.w;
            acc[1][0] += a.y * b.x; acc[1][1] += a.y * b.y;
            acc[1][2] += a.y * b.z; acc[1][3] += a.y * b.w;
            acc[2][0] += a.z * b.x; acc[2][1] += a.z * b.y;
            acc[2][2] += a.z * b.z; acc[2][3] += a.z * b.w;
            acc[3][0] += a.w * b.x; acc[3][1] += a.w * b.y;
            acc[3][2] += a.w * b.z; acc[3][3] += a.w * b.w;
        }
    }
    #pragma unroll
    for (int i = 0; i < 4; ++i) {
        const int m = m0 + (ty << 2) + i;
        if (m < M) {
            #pragma unroll
            for (int j = 0; j < 4; ++j) {
                const int n = n0 + (tx << 2) + j;
                if (n < N) C[(size_t)m * ldc + n] = acc[i][j];
            }
        }
    }
}

// ---------------------------------------------------------------------------
// fp32 NN GEMM + fused bias+softplus (dt_proj).
// ---------------------------------------------------------------------------
__global__ __launch_bounds__(256)
void gemm_nn_softplus(const float* __restrict__ A, const float* __restrict__ B,
                      const float* __restrict__ bias, float* __restrict__ C,
                      int K, int lda, int ldb, int ldc) {
    __shared__ float As[16][64];
    __shared__ float Bs[16][64];
    const int t = threadIdx.x;
    const int tx = t & 15, ty = t >> 4;
    const int m0 = blockIdx.y * 64, n0 = blockIdx.x * 64;
    const int ar = t >> 2, ak = (t & 3) << 2;
    const int bk = t >> 4, bn = (t & 15) << 2;
    float acc[4][4] = {};

    for (int k0 = 0; k0 < K; k0 += 16) {
        const float4 av = *(const float4*)(A + (size_t)(m0 + ar) * lda + k0 + ak);
        const float4 bv = *(const float4*)(B + (size_t)(k0 + bk) * ldb + n0 + bn);
        __syncthreads();
        As[ak + 0][ar] = av.x; As[ak + 1][ar] = av.y;
        As[ak + 2][ar] = av.z; As[ak + 3][ar] = av.w;
        *(float4*)&Bs[bk][bn] = bv;
        __syncthreads();
        #pragma unroll
        for (int k = 0; k < 16; ++k) {
            const float4 a = *(const float4*)&As[k][ty << 2];
            const float4 b = *(const float4*)&Bs[k][tx << 2];
            acc[0][0] += a.x * b.x; acc[0][1] += a.x * b.y;
            acc[0][2] += a.x * b.z; acc[0][3] += a.x * b.w;
            acc[1][0] += a.y * b.x; acc[1][1] += a.y * b.y;
            acc[1][2] += a.y * b.z; acc[1][3] += a.y * b.w;
            acc[2][0] += a.z * b.x; acc[2][1] += a.z * b.y;
            acc[2][2] += a.z * b.z; acc[2][3] += a.z * b.w;
            acc[3][0] += a.w * b.x; acc[3][1] += a.w * b.y;
            acc[3][2] += a.w * b.z; acc[3][3] += a.w * b.w;
        }
    }
    #pragma unroll
    for (int i = 0; i < 4; ++i) {
        const int m = m0 + (ty << 2) + i;
        const float bb = bias[m];
        #pragma unroll
        for (int j = 0; j < 4; ++j) {
            const int n = n0 + (tx << 2) + j;
            const float v = acc[i][j] + bb;
            C[(size_t)m * ldc + n] = (v > 20.f) ? v : log1pf(expf(v));
        }
    }
}

// ---------------------------------------------------------------------------
// fp32 NN GEMM split-K w/ atomicAdd (x_proj, M=96). C zeroed first.
// ---------------------------------------------------------------------------
__global__ __launch_bounds__(256)
void gemm_nn_splitk(const float* __restrict__ A, const float* __restrict__ B,
                    float* __restrict__ C, int lda, int ldb, int ldc, int kchunk) {
    __shared__ float As[32][32];
    __shared__ float Bs[32][64];
    const int t = threadIdx.x;
    const int tx = t & 15, ty = t >> 4;
    const int m0 = blockIdx.y * 32, n0 = blockIdx.x * 64;
    const int k0s = blockIdx.z * kchunk;
    const int ar = t >> 3, ak = (t & 7) << 2;
    const int bk = t >> 4, bn = (t & 15) << 2;
    float acc[2][4] = {};

    for (int k0 = k0s; k0 < k0s + kchunk; k0 += 32) {
        const float4 av = *(const float4*)(A + (size_t)(m0 + ar) * lda + k0 + ak);
        const float4 bv0 = *(const float4*)(B + (size_t)(k0 + bk) * ldb + n0 + bn);
        const float4 bv1 = *(const float4*)(B + (size_t)(k0 + bk + 16) * ldb + n0 + bn);
        __syncthreads();
        As[ak + 0][ar] = av.x; As[ak + 1][ar] = av.y;
        As[ak + 2][ar] = av.z; As[ak + 3][ar] = av.w;
        *(float4*)&Bs[bk][bn] = bv0;
        *(float4*)&Bs[bk + 16][bn] = bv1;
        __syncthreads();
        #pragma unroll
        for (int k = 0; k < 32; ++k) {
            const float a0 = As[k][(ty << 1) + 0];
            const float a1 = As[k][(ty << 1) + 1];
            const float4 b = *(const float4*)&Bs[k][tx << 2];
            acc[0][0] += a0 * b.x; acc[0][1] += a0 * b.y;
            acc[0][2] += a0 * b.z; acc[0][3] += a0 * b.w;
            acc[1][0] += a1 * b.x; acc[1][1] += a1 * b.y;
            acc[1][2] += a1 * b.z; acc[1][3] += a1 * b.w;
        }
    }
    #pragma unroll
    for (int i = 0; i < 2; ++i) {
        const int m = m0 + (ty << 1) + i;
        #pragma unroll
        for (int j = 0; j < 4; ++j)
            atomicAdd(&C[(size_t)m * ldc + n0 + (tx << 2) + j], acc[i][j]);
    }
}

// ---------------------------------------------------------------------------
__global__ __launch_bounds__(256)
void zero_f32(float* __restrict__ p, int n) {
    const int i = blockIdx.x * 256 + threadIdx.x;
    if (i < n) p[i] = 0.f;
}

__global__ __launch_bounds__(256)
void cast_f32_bf16(const float* __restrict__ in, __hip_bfloat16* __restrict__ out,
                   int n4) {
    const int i = blockIdx.x * 256 + threadIdx.x;
    if (i < n4) {
        const float4 v = *(const float4*)(in + (size_t)i * 4);
        __hip_bfloat16 h0 = __float2bfloat16(v.x), h1 = __float2bfloat16(v.y);
        __hip_bfloat16 h2 = __float2bfloat16(v.z), h3 = __float2bfloat16(v.w);
        ushort4 p;
        p.x = *(unsigned short*)&h0; p.y = *(unsigned short*)&h1;
        p.z = *(unsigned short*)&h2; p.w = *(unsigned short*)&h3;
        *(ushort4*)((unsigned short*)out + (size_t)i * 4) = p;
    }
}

// ---------------------------------------------------------------------------
// Transpose B/C rows of xdbl_T into xbc[l][32]: col s = B_s, col 16+s = C_s.
// ---------------------------------------------------------------------------
__global__ __launch_bounds__(256)
void transpose_bc(const float* __restrict__ xdbl_T, float* __restrict__ xbc) {
    __shared__ float tile[32][33];
    const int t = threadIdx.x;
    const int l0 = blockIdx.x * 32;
    const int s = t >> 3, lc = (t & 7) << 2;
    const float4 v = *(const float4*)(xdbl_T + (size_t)(DTRANK + s) * L_SEQ + l0 + lc);
    tile[s][lc + 0] = v.x; tile[s][lc + 1] = v.y;
    tile[s][lc + 2] = v.z; tile[s][lc + 3] = v.w;
    __syncthreads();
    const int l = t >> 3, sc = (t & 7) << 2;
    float4 w;
    w.x = tile[sc + 0][l]; w.y = tile[sc + 1][l];
    w.z = tile[sc + 2][l]; w.w = tile[sc + 3][l];
    *(float4*)(xbc + (size_t)(l0 + l) * 32 + sc) = w;
}

// ---------------------------------------------------------------------------
// bf16 transpose: out[Cc][R] = in[R][Cc]^T. 64x64 tiles.
// ---------------------------------------------------------------------------
__global__ __launch_bounds__(256)
void transpose_bf16(const unsigned short* __restrict__ in,
                    unsigned short* __restrict__ out, int R, int Cc) {
    __shared__ unsigned short tile[64][65];
    const int t = threadIdx.x;
    const int r0 = blockIdx.y * 64, c0 = blockIdx.x * 64;
    const int tr = t >> 3, tc8 = (t & 7) << 3;
    #pragma unroll
    for (int i = 0; i < 2; ++i) {
        const int r = tr + i * 32;
        const ushort4 v0 = *(const ushort4*)(in + (size_t)(r0 + r) * Cc + c0 + tc8);
        const ushort4 v1 = *(const ushort4*)(in + (size_t)(r0 + r) * Cc + c0 + tc8 + 4);
        tile[r][tc8 + 0] = v0.x; tile[r][tc8 + 1] = v0.y;
        tile[r][tc8 + 2] = v0.z; tile[r][tc8 + 3] = v0.w;
        tile[r][tc8 + 4] = v1.x; tile[r][tc8 + 5] = v1.y;
        tile[r][tc8 + 6] = v1.z; tile[r][tc8 + 7] = v1.w;
    }
    __syncthreads();
    #pragma unroll
    for (int i = 0; i < 2; ++i) {
        const int r = tr + i * 32;
        ushort4 w0, w1;
        w0.x = tile[tc8 + 0][r]; w0.y = tile[tc8 + 1][r];
        w0.z = tile[tc8 + 2][r]; w0.w = tile[tc8 + 3][r];
        w1.x = tile[tc8 + 4][r]; w1.y = tile[tc8 + 5][r];
        w1.z = tile[tc8 + 6][r]; w1.w = tile[tc8 + 7][r];
        *(ushort4*)(out + (size_t)(c0 + r) * R + r0 + tc8)     = w0;
        *(ushort4*)(out + (size_t)(c0 + r) * R + r0 + tc8 + 4) = w1;
    }
}

// ---------------------------------------------------------------------------
// Residual add + LayerNorm -> bf16. One block per row l.
// ---------------------------------------------------------------------------
__global__ __launch_bounds__(256)
void add_ln(const float* __restrict__ h, float* __restrict__ res,
            __hip_bfloat16* __restrict__ hn, const float* __restrict__ w,
            const float* __restrict__ b, int is_first) {
    const int l = blockIdx.x;
    const int t = threadIdx.x;
    float v[4];
    float s = 0.f, ss = 0.f;
    #pragma unroll
    for (int j = 0; j < 4; ++j) {
        const int d = t + j * 256;
        float x = h[(size_t)l * DMODEL + d];
        if (!is_first) x += res[(size_t)l * DMODEL + d];
        res[(size_t)l * DMODEL + d] = x;
        v[j] = x; s += x; ss += x * x;
    }
    #pragma unroll
    for (int o = 32; o > 0; o >>= 1) {
        s  += __shfl_down(s, o);
        ss += __shfl_down(ss, o);
    }
    __shared__ float sm[4], sm2[4];
    const int wid = t >> 6;
    if ((t & 63) == 0) { sm[wid] = s; sm2[wid] = ss; }
    __syncthreads();
    s  = sm[0] + sm[1] + sm[2] + sm[3];
    ss = sm2[0] + sm2[1] + sm2[2] + sm2[3];
    const float mu  = s * (1.f / DMODEL);
    const float var = ss * (1.f / DMODEL) - mu * mu;
    const float r   = rsqrtf(var + LN_EPS);
    #pragma unroll
    for (int j = 0; j < 4; ++j) {
        const int d = t + j * 256;
        hn[(size_t)l * DMODEL + d] = __float2bfloat16((v[j] - mu) * r * w[d] + b[d]);
    }
}

// ---------------------------------------------------------------------------
// Depthwise causal conv + bias + SiLU, transposed layout. Block = channel d.
// ---------------------------------------------------------------------------
__global__ __launch_bounds__(256)
void conv_silu_t(const float* __restrict__ xz_T, float* __restrict__ xc_T,
                 const float* __restrict__ cw, const float* __restrict__ cb) {
    const int d = blockIdx.x;
    const int t = threadIdx.x;
    __shared__ float row[L_SEQ];
    *(float4*)&row[t << 2] = *(const float4*)(xz_T + (size_t)d * L_SEQ + (t << 2));
    __syncthreads();
    const float w0 = cw[d * 4 + 0], w1 = cw[d * 4 + 1];
    const float w2 = cw[d * 4 + 2], w3 = cw[d * 4 + 3];
    const float bb = cb[d];
    float o[4];
    #pragma unroll
    for (int j = 0; j < 4; ++j) {
        const int l = (t << 2) + j;
        float acc = bb + w3 * row[l];
        if (l >= 1) acc += w2 * row[l - 1];
        if (l >= 2) acc += w1 * row[l - 2];
        if (l >= 3) acc += w0 * row[l - 3];
        const float sig = 1.f / (1.f + __expf(-acc));
        o[j] = acc * sig;
    }
    *(float4*)(xc_T + (size_t)d * L_SEQ + (t << 2)) = make_float4(o[0], o[1], o[2], o[3]);
}

// ---------------------------------------------------------------------------
// Chunk-parallel selective scan v2. Block = channel d, 1024 threads.
// Thread (s, c): s = state 0..15, c = chunk 0..63 (16 steps each).
// Phase 1 caches prefix products ap[] and local states hl[] in registers;
// phase 3 is the closed form h_j = h0*ap[j] + hl[j] (no exp, no B-reload).
// ---------------------------------------------------------------------------
__global__ __launch_bounds__(1024)
void ssm_scan_t2(const float* __restrict__ delta_T,
                 const float* __restrict__ xc_T,
                 const float* __restrict__ xbc,
                 const float* __restrict__ xz_T,
                 const float* __restrict__ alog,
                 const float* __restrict__ dsk,
                 __hip_bfloat16* __restrict__ y_T) {
    const int d = blockIdx.x;
    const int t = threadIdx.x;
    const int s = t & 15;
    const int c = t >> 4;          // 0..63

    __shared__ float sdl[L_SEQ + 32], sxl[L_SEQ + 32];
    __shared__ float sz[L_SEQ], sy[L_SEQ];
    __shared__ float saprod[NCHUNK][DSTATE];
    __shared__ float shloc[NCHUNK][DSTATE];
    __shared__ float shstart[NCHUNK][DSTATE];

    if (t < 256) {
        const float4 v = ((const float4*)(delta_T + (size_t)d * L_SEQ))[t];
        const int l = t << 2;
        sdl[SK(l)] = v.x; sdl[SK(l + 1)] = v.y;
        sdl[SK(l + 2)] = v.z; sdl[SK(l + 3)] = v.w;
    } else if (t < 512) {
        const int tt = t - 256;
        const float4 v = ((const float4*)(xc_T + (size_t)d * L_SEQ))[tt];
        const int l = tt << 2;
        sxl[SK(l)] = v.x; sxl[SK(l + 1)] = v.y;
        sxl[SK(l + 2)] = v.z; sxl[SK(l + 3)] = v.w;
    } else if (t < 768) {
        ((float4*)sz)[t - 512] =
            ((const float4*)(xz_T + (size_t)(DINNER + d) * L_SEQ))[t - 512];
    }
    __syncthreads();

    const float A  = -expf(alog[d * DSTATE + s]);
    const int   l0 = c * CHUNK;

    // Phase 1: local scan with h0 = 0; cache prefix (ap, hl) in registers.
    float ap[CHUNK], hl[CHUNK];
    float aprod = 1.f, h = 0.f;
    #pragma unroll
    for (int j = 0; j < CHUNK; ++j) {
        const int l = l0 + j;
        const float dl = sdl[SK(l)];
        const float da = __expf(dl * A);
        h = da * h + dl * xbc[(size_t)l * 32 + s] * sxl[SK(l)];
        aprod *= da;
        ap[j] = aprod; hl[j] = h;
    }
    saprod[c][s] = aprod;
    shloc[c][s]  = h;
    __syncthreads();

    // Phase 2: serial combine across 64 chunk summaries (16 threads).
    if (t < 16) {
        float hs = 0.f;
        for (int cc = 0; cc < NCHUNK; ++cc) {
            shstart[cc][t] = hs;
            hs = saprod[cc][t] * hs + shloc[cc][t];
        }
    }
    __syncthreads();

    // Phase 3: closed-form rescan, produce y.
    const float h0 = shstart[c][s];
    const float Dk = dsk[d];
    #pragma unroll
    for (int j = 0; j < CHUNK; ++j) {
        const int l = l0 + j;
        const float hj = h0 * ap[j] + hl[j];
        float cch = hj * xbc[(size_t)l * 32 + 16 + s];
        cch += __shfl_xor(cch, 1, 16);
        cch += __shfl_xor(cch, 2, 16);
        cch += __shfl_xor(cch, 4, 16);
        cch += __shfl_xor(cch, 8, 16);
        if (s == 0) {
            const float xl  = sxl[SK(l)];
            const float zl  = sz[l];
            const float sig = 1.f / (1.f + __expf(-zl));
            sy[l] = (cch + xl * Dk) * (zl * sig);
        }
    }
    __syncthreads();

    if (t < 256) {
        const float4 v = ((const float4*)sy)[t];
        __hip_bfloat16 h0b = __float2bfloat16(v.x), h1b = __float2bfloat16(v.y);
        __hip_bfloat16 h2b = __float2bfloat16(v.z), h3b = __float2bfloat16(v.w);
        ushort4 p;
        p.x = *(unsigned short*)&h0b; p.y = *(unsigned short*)&h1b;
        p.z = *(unsigned short*)&h2b; p.w = *(unsigned short*)&h3b;
        *(ushort4*)((unsigned short*)y_T + (size_t)d * L_SEQ + (t << 2)) = p;
    }
}

// ---------------------------------------------------------------------------
extern "C" void kernel_launch(void* const* d_in, const int* in_sizes, int n_in,
                              void* d_out, int out_size, void* d_ws, size_t ws_size,
                              hipStream_t stream) {
    const float* input   = (const float*)d_in[0];
    const float* input_w = (const float*)d_in[2];
    const float* norm_w  = (const float*)d_in[3];
    const float* norm_b  = (const float*)d_in[4];
    const float* ipw     = (const float*)d_in[5];
    const float* cw      = (const float*)d_in[6];
    const float* cb      = (const float*)d_in[7];
    const float* xpw     = (const float*)d_in[8];
    const float* dtw     = (const float*)d_in[9];
    const float* dtb     = (const float*)d_in[10];
    const float* alog    = (const float*)d_in[11];
    const float* dsk     = (const float*)d_in[12];
    const float* opw     = (const float*)d_in[13];
    float* out = (float*)d_out;

    float* ws      = (float*)d_ws;
    float* h       = ws;                        // 1M floats
    float* res     = h       + (1u << 20);      // 1M
    float* xz_T    = res     + (1u << 20);      // 4M   [e][l]
    float* xc_T    = xz_T    + (4u << 20);      // 2M   [d][l]
    float* xdbl_T  = xc_T    + (2u << 20);      // 96*1024  [e][l]
    float* xbc     = xdbl_T  + (NXP * L_SEQ);   // 1024*32  [l][32]
    float* delta_T = xbc     + (L_SEQ * 32);    // 2M   [d][l]
    __hip_bfloat16* hn_bf  = (__hip_bfloat16*)(delta_T + (2u << 20));  // 1M halfs
    __hip_bfloat16* yT_bf  = hn_bf  + (1u << 20);                      // 2M halfs
    __hip_bfloat16* y_bf   = yT_bf  + (2u << 20);                      // 2M halfs
    __hip_bfloat16* ipw_bf = y_bf   + (2u << 20);                      // 4M halfs
    __hip_bfloat16* opw_bf = ipw_bf + (4u << 20);                      // 2M halfs

    const dim3 blk(256);

    // h = input @ input_w^T   (runs once, fp32)
    gemm_nt<<<dim3(DMODEL / 64, L_SEQ / 64), blk, 0, stream>>>(
        input, input_w, h, L_SEQ, DMODEL, 512, 512, 512, DMODEL);

    for (int i = 0; i < 4; ++i) {
        cast_f32_bf16<<<(2 * DINNER * DMODEL / 4 + 255) / 256, blk, 0, stream>>>(
            ipw + (size_t)i * 2 * DINNER * DMODEL, ipw_bf, 2 * DINNER * DMODEL / 4);

        add_ln<<<L_SEQ, 256, 0, stream>>>(
            h, res, hn_bf, norm_w + i * DMODEL, norm_b + i * DMODEL, i == 0);

        // xz_T[e][l] = ipw @ hn^T   (M=4096, N=1024, K=1024) bf16 MFMA
        gemm_bt_bf16<<<dim3(L_SEQ / 128, 2 * DINNER / 128), blk, 0, stream>>>(
            ipw_bf, hn_bf, xz_T, DMODEL, DMODEL, DMODEL, L_SEQ);

        // xc_T[d][l] = silu(conv(x) + cb)
        conv_silu_t<<<DINNER, 256, 0, stream>>>(
            xz_T, xc_T, cw + i * DINNER * 4, cb + i * DINNER);

        // xdbl_T[e][l] = xpw @ xc_T   (M=96, N=1024, K=2048) fp32 split-K
        zero_f32<<<(NXP * L_SEQ + 255) / 256, blk, 0, stream>>>(xdbl_T, NXP * L_SEQ);
        gemm_nn_splitk<<<dim3(L_SEQ / 64, 3, 8), blk, 0, stream>>>(
            xpw + (size_t)i * NXP * DINNER, xc_T, xdbl_T,
            DINNER, L_SEQ, L_SEQ, DINNER / 8);

        // xbc[l][32] = (B|C) in line-friendly layout
        transpose_bc<<<L_SEQ / 32, 256, 0, stream>>>(xdbl_T, xbc);

        // delta_T[d][l] = softplus(dtw @ xdbl_T[:64] + dtb)
        gemm_nn_softplus<<<dim3(L_SEQ / 64, DINNER / 64), blk, 0, stream>>>(
            dtw + (size_t)i * DINNER * DTRANK, xdbl_T, dtb + i * DINNER, delta_T,
            DTRANK, DTRANK, L_SEQ, L_SEQ);

        ssm_scan_t2<<<DINNER, 1024, 0, stream>>>(
            delta_T, xc_T, xbc, xz_T,
            alog + i * DINNER * DSTATE, dsk + i * DINNER, yT_bf);

        // y_bf[l][d] = yT_bf^T
        transpose_bf16<<<dim3(L_SEQ / 64, DINNER / 64), blk, 0, stream>>>(
            (const unsigned short*)yT_bf, (unsigned short*)y_bf, DINNER, L_SEQ);

        // out = y @ opw^T   (M=1024, N=1024, K=2048) bf16 MFMA split-K x4
        cast_f32_bf16<<<(DMODEL * DINNER / 4 + 255) / 256, blk, 0, stream>>>(
            opw + (size_t)i * DMODEL * DINNER, opw_bf, DMODEL * DINNER / 4);
        float* dst = (i == 3) ? out : h;
        zero_f32<<<(L_SEQ * DMODEL + 255) / 256, blk, 0, stream>>>(dst, L_SEQ * DMODEL);
        gemm_bt_bf16_sk<<<dim3(DMODEL / 128, L_SEQ / 128, 4), blk, 0, stream>>>(
            y_bf, opw_bf, dst, DINNER / 4, DINNER, DINNER, DMODEL);
    }
}

// Round 7
// 829.403 us; speedup vs baseline: 1.1010x; 1.1010x over previous
//
#include <hip/hip_runtime.h>
#include <hip/hip_bf16.h>
#include <math.h>

#define L_SEQ   1024
#define DMODEL  1024
#define DINNER  2048
#define DSTATE  16
#define DTRANK  64
#define NXP     96      // DTRANK + 2*DSTATE
#define LN_EPS  1e-5f
#define CHUNK   32
#define NCHUNK  (L_SEQ / CHUNK)      // 32
#define SK(l)   ((l) + ((l) >> 5))   // LDS skew: kills 4-way bank conflict

typedef __bf16 bf16x8 __attribute__((ext_vector_type(8)));
typedef float  f32x4  __attribute__((ext_vector_type(4)));

// ---------------------------------------------------------------------------
// bf16 MFMA GEMM (m97 structure): C[M,N] = A[M,K] @ W[N,K]^T, fp32 out.
// ---------------------------------------------------------------------------
__global__ __launch_bounds__(256)
void gemm_bt_bf16(const __hip_bfloat16* __restrict__ A,
                  const __hip_bfloat16* __restrict__ W,
                  float* __restrict__ C,
                  int K, int lda, int ldb, int ldc) {
    __shared__ __hip_bfloat16 As[128][32];
    __shared__ __hip_bfloat16 Bs[128][32];
    const int tid  = threadIdx.x;
    const int lane = tid & 63;
    const int wave = tid >> 6;
    const int m0 = blockIdx.y * 128, n0 = blockIdx.x * 128;
    const int wm = (wave >> 1) * 64, wn = (wave & 1) * 64;
    const int srow = tid >> 2, skcol = (tid & 3) << 3;
    const int fm = lane & 15, fk = (lane >> 4) << 3;

    f32x4 acc[4][4] = {};

    const __hip_bfloat16* Ap0 = A + (size_t)(m0 + srow) * lda + skcol;
    const __hip_bfloat16* Ap1 = Ap0 + (size_t)64 * lda;
    const __hip_bfloat16* Wp0 = W + (size_t)(n0 + srow) * ldb + skcol;
    const __hip_bfloat16* Wp1 = Wp0 + (size_t)64 * ldb;

    for (int k0 = 0; k0 < K; k0 += 32) {
        __syncthreads();
        __builtin_amdgcn_global_load_lds(
            (const __attribute__((address_space(1))) unsigned int*)(Ap0 + k0),
            (__attribute__((address_space(3))) unsigned int*)&As[srow][skcol], 16, 0, 0);
        __builtin_amdgcn_global_load_lds(
            (const __attribute__((address_space(1))) unsigned int*)(Ap1 + k0),
            (__attribute__((address_space(3))) unsigned int*)&As[64 + srow][skcol], 16, 0, 0);
        __builtin_amdgcn_global_load_lds(
            (const __attribute__((address_space(1))) unsigned int*)(Wp0 + k0),
            (__attribute__((address_space(3))) unsigned int*)&Bs[srow][skcol], 16, 0, 0);
        __builtin_amdgcn_global_load_lds(
            (const __attribute__((address_space(1))) unsigned int*)(Wp1 + k0),
            (__attribute__((address_space(3))) unsigned int*)&Bs[64 + srow][skcol], 16, 0, 0);
        __syncthreads();

        bf16x8 af[4], bfr[4];
        #pragma unroll
        for (int i = 0; i < 4; ++i) {
            af[i]  = *(const bf16x8*)&As[wm + i * 16 + fm][fk];
            bfr[i] = *(const bf16x8*)&Bs[wn + i * 16 + fm][fk];
        }
        #pragma unroll
        for (int mt = 0; mt < 4; ++mt)
            #pragma unroll
            for (int nt = 0; nt < 4; ++nt)
                acc[mt][nt] = __builtin_amdgcn_mfma_f32_16x16x32_bf16(
                    af[mt], bfr[nt], acc[mt][nt], 0, 0, 0);
    }

    const int crow = (lane >> 4) << 2;
    const int ccol = lane & 15;
    #pragma unroll
    for (int mt = 0; mt < 4; ++mt)
        #pragma unroll
        for (int nt = 0; nt < 4; ++nt) {
            float* cp = C + (size_t)(m0 + wm + mt * 16 + crow) * ldc
                          + n0 + wn + nt * 16 + ccol;
            #pragma unroll
            for (int r = 0; r < 4; ++r) cp[(size_t)r * ldc] = acc[mt][nt][r];
        }
}

// ---------------------------------------------------------------------------
// Split-K variant: grid.z slices K; atomicAdd fp32 epilogue (C zeroed first).
// ---------------------------------------------------------------------------
__global__ __launch_bounds__(256)
void gemm_bt_bf16_sk(const __hip_bfloat16* __restrict__ A,
                     const __hip_bfloat16* __restrict__ W,
                     float* __restrict__ C,
                     int kchunk, int lda, int ldb, int ldc) {
    __shared__ __hip_bfloat16 As[128][32];
    __shared__ __hip_bfloat16 Bs[128][32];
    const int tid  = threadIdx.x;
    const int lane = tid & 63;
    const int wave = tid >> 6;
    const int m0 = blockIdx.y * 128, n0 = blockIdx.x * 128;
    const int k0s = blockIdx.z * kchunk;
    const int wm = (wave >> 1) * 64, wn = (wave & 1) * 64;
    const int srow = tid >> 2, skcol = (tid & 3) << 3;
    const int fm = lane & 15, fk = (lane >> 4) << 3;

    f32x4 acc[4][4] = {};

    const __hip_bfloat16* Ap0 = A + (size_t)(m0 + srow) * lda + skcol;
    const __hip_bfloat16* Ap1 = Ap0 + (size_t)64 * lda;
    const __hip_bfloat16* Wp0 = W + (size_t)(n0 + srow) * ldb + skcol;
    const __hip_bfloat16* Wp1 = Wp0 + (size_t)64 * ldb;

    for (int k0 = k0s; k0 < k0s + kchunk; k0 += 32) {
        __syncthreads();
        __builtin_amdgcn_global_load_lds(
            (const __attribute__((address_space(1))) unsigned int*)(Ap0 + k0),
            (__attribute__((address_space(3))) unsigned int*)&As[srow][skcol], 16, 0, 0);
        __builtin_amdgcn_global_load_lds(
            (const __attribute__((address_space(1))) unsigned int*)(Ap1 + k0),
            (__attribute__((address_space(3))) unsigned int*)&As[64 + srow][skcol], 16, 0, 0);
        __builtin_amdgcn_global_load_lds(
            (const __attribute__((address_space(1))) unsigned int*)(Wp0 + k0),
            (__attribute__((address_space(3))) unsigned int*)&Bs[srow][skcol], 16, 0, 0);
        __builtin_amdgcn_global_load_lds(
            (const __attribute__((address_space(1))) unsigned int*)(Wp1 + k0),
            (__attribute__((address_space(3))) unsigned int*)&Bs[64 + srow][skcol], 16, 0, 0);
        __syncthreads();

        bf16x8 af[4], bfr[4];
        #pragma unroll
        for (int i = 0; i < 4; ++i) {
            af[i]  = *(const bf16x8*)&As[wm + i * 16 + fm][fk];
            bfr[i] = *(const bf16x8*)&Bs[wn + i * 16 + fm][fk];
        }
        #pragma unroll
        for (int mt = 0; mt < 4; ++mt)
            #pragma unroll
            for (int nt = 0; nt < 4; ++nt)
                acc[mt][nt] = __builtin_amdgcn_mfma_f32_16x16x32_bf16(
                    af[mt], bfr[nt], acc[mt][nt], 0, 0, 0);
    }

    const int crow = (lane >> 4) << 2;
    const int ccol = lane & 15;
    #pragma unroll
    for (int mt = 0; mt < 4; ++mt)
        #pragma unroll
        for (int nt = 0; nt < 4; ++nt) {
            float* cp = C + (size_t)(m0 + wm + mt * 16 + crow) * ldc
                          + n0 + wn + nt * 16 + ccol;
            #pragma unroll
            for (int r = 0; r < 4; ++r)
                atomicAdd(&cp[(size_t)r * ldc], acc[mt][nt][r]);
        }
}

// ---------------------------------------------------------------------------
// fp32 tiled GEMM NT (first projection only).
// ---------------------------------------------------------------------------
__global__ __launch_bounds__(256)
void gemm_nt(const float* __restrict__ A, const float* __restrict__ W,
             float* __restrict__ C, int M, int N, int K,
             int lda, int ldb, int ldc) {
    __shared__ float As[16][64];
    __shared__ float Bs[16][64];
    const int tid = threadIdx.x;
    const int tx = tid & 15, ty = tid >> 4;
    const int m0 = blockIdx.y * 64, n0 = blockIdx.x * 64;
    const int lr = tid >> 2;
    const int lk = (tid & 3) << 2;
    float acc[4][4] = {};

    for (int k0 = 0; k0 < K; k0 += 16) {
        float4 av = make_float4(0.f, 0.f, 0.f, 0.f);
        float4 bv = make_float4(0.f, 0.f, 0.f, 0.f);
        const int am = m0 + lr;
        if (am < M) av = *(const float4*)(A + (size_t)am * lda + k0 + lk);
        const int bn = n0 + lr;
        if (bn < N) bv = *(const float4*)(W + (size_t)bn * ldb + k0 + lk);
        __syncthreads();
        As[lk + 0][lr] = av.x; As[lk + 1][lr] = av.y;
        As[lk + 2][lr] = av.z; As[lk + 3][lr] = av.w;
        Bs[lk + 0][lr] = bv.x; Bs[lk + 1][lr] = bv.y;
        Bs[lk + 2][lr] = bv.z; Bs[lk + 3][lr] = bv.w;
        __syncthreads();
        #pragma unroll
        for (int k = 0; k < 16; ++k) {
            const float4 a = *(const float4*)&As[k][ty << 2];
            const float4 b = *(const float4*)&Bs[k][tx << 2];
            acc[0][0] += a.x * b.x; acc[0][1] += a.x * b.y;
            acc[0][2] += a.x * b.z; acc[0][3] += a.x * b.w;
            acc[1][0] += a.y * b.x; acc[1][1] += a.y * b.y;
            acc[1][2] += a.y * b.z; acc[1][3] += a.y * b.w;
            acc[2][0] += a.z * b.x; acc[2][1] += a.z * b.y;
            acc[2][2] += a.z * b.z; acc[2][3] += a.z * b.w;
            acc[3][0] += a.w * b.x; acc[3][1] += a.w * b.y;
            acc[3][2] += a.w * b.z; acc[3][3] += a.w * b.w;
        }
    }
    #pragma unroll
    for (int i = 0; i < 4; ++i) {
        const int m = m0 + (ty << 2) + i;
        if (m < M) {
            #pragma unroll
            for (int j = 0; j < 4; ++j) {
                const int n = n0 + (tx << 2) + j;
                if (n < N) C[(size_t)m * ldc + n] = acc[i][j];
            }
        }
    }
}

// ---------------------------------------------------------------------------
// fp32 NN GEMM + fused bias+softplus (dt_proj).
// ---------------------------------------------------------------------------
__global__ __launch_bounds__(256)
void gemm_nn_softplus(const float* __restrict__ A, const float* __restrict__ B,
                      const float* __restrict__ bias, float* __restrict__ C,
                      int K, int lda, int ldb, int ldc) {
    __shared__ float As[16][64];
    __shared__ float Bs[16][64];
    const int t = threadIdx.x;
    const int tx = t & 15, ty = t >> 4;
    const int m0 = blockIdx.y * 64, n0 = blockIdx.x * 64;
    const int ar = t >> 2, ak = (t & 3) << 2;
    const int bk = t >> 4, bn = (t & 15) << 2;
    float acc[4][4] = {};

    for (int k0 = 0; k0 < K; k0 += 16) {
        const float4 av = *(const float4*)(A + (size_t)(m0 + ar) * lda + k0 + ak);
        const float4 bv = *(const float4*)(B + (size_t)(k0 + bk) * ldb + n0 + bn);
        __syncthreads();
        As[ak + 0][ar] = av.x; As[ak + 1][ar] = av.y;
        As[ak + 2][ar] = av.z; As[ak + 3][ar] = av.w;
        *(float4*)&Bs[bk][bn] = bv;
        __syncthreads();
        #pragma unroll
        for (int k = 0; k < 16; ++k) {
            const float4 a = *(const float4*)&As[k][ty << 2];
            const float4 b = *(const float4*)&Bs[k][tx << 2];
            acc[0][0] += a.x * b.x; acc[0][1] += a.x * b.y;
            acc[0][2] += a.x * b.z; acc[0][3] += a.x * b.w;
            acc[1][0] += a.y * b.x; acc[1][1] += a.y * b.y;
            acc[1][2] += a.y * b.z; acc[1][3] += a.y * b.w;
            acc[2][0] += a.z * b.x; acc[2][1] += a.z * b.y;
            acc[2][2] += a.z * b.z; acc[2][3] += a.z * b.w;
            acc[3][0] += a.w * b.x; acc[3][1] += a.w * b.y;
            acc[3][2] += a.w * b.z; acc[3][3] += a.w * b.w;
        }
    }
    #pragma unroll
    for (int i = 0; i < 4; ++i) {
        const int m = m0 + (ty << 2) + i;
        const float bb = bias[m];
        #pragma unroll
        for (int j = 0; j < 4; ++j) {
            const int n = n0 + (tx << 2) + j;
            const float v = acc[i][j] + bb;
            C[(size_t)m * ldc + n] = (v > 20.f) ? v : log1pf(expf(v));
        }
    }
}

// ---------------------------------------------------------------------------
// fp32 NN GEMM split-K w/ atomicAdd (x_proj, M=96). C zeroed first.
// ---------------------------------------------------------------------------
__global__ __launch_bounds__(256)
void gemm_nn_splitk(const float* __restrict__ A, const float* __restrict__ B,
                    float* __restrict__ C, int lda, int ldb, int ldc, int kchunk) {
    __shared__ float As[32][32];
    __shared__ float Bs[32][64];
    const int t = threadIdx.x;
    const int tx = t & 15, ty = t >> 4;
    const int m0 = blockIdx.y * 32, n0 = blockIdx.x * 64;
    const int k0s = blockIdx.z * kchunk;
    const int ar = t >> 3, ak = (t & 7) << 2;
    const int bk = t >> 4, bn = (t & 15) << 2;
    float acc[2][4] = {};

    for (int k0 = k0s; k0 < k0s + kchunk; k0 += 32) {
        const float4 av = *(const float4*)(A + (size_t)(m0 + ar) * lda + k0 + ak);
        const float4 bv0 = *(const float4*)(B + (size_t)(k0 + bk) * ldb + n0 + bn);
        const float4 bv1 = *(const float4*)(B + (size_t)(k0 + bk + 16) * ldb + n0 + bn);
        __syncthreads();
        As[ak + 0][ar] = av.x; As[ak + 1][ar] = av.y;
        As[ak + 2][ar] = av.z; As[ak + 3][ar] = av.w;
        *(float4*)&Bs[bk][bn] = bv0;
        *(float4*)&Bs[bk + 16][bn] = bv1;
        __syncthreads();
        #pragma unroll
        for (int k = 0; k < 32; ++k) {
            const float a0 = As[k][(ty << 1) + 0];
            const float a1 = As[k][(ty << 1) + 1];
            const float4 b = *(const float4*)&Bs[k][tx << 2];
            acc[0][0] += a0 * b.x; acc[0][1] += a0 * b.y;
            acc[0][2] += a0 * b.z; acc[0][3] += a0 * b.w;
            acc[1][0] += a1 * b.x; acc[1][1] += a1 * b.y;
            acc[1][2] += a1 * b.z; acc[1][3] += a1 * b.w;
        }
    }
    #pragma unroll
    for (int i = 0; i < 2; ++i) {
        const int m = m0 + (ty << 1) + i;
        #pragma unroll
        for (int j = 0; j < 4; ++j)
            atomicAdd(&C[(size_t)m * ldc + n0 + (tx << 2) + j], acc[i][j]);
    }
}

// ---------------------------------------------------------------------------
// Zero two buffers in one dispatch.
// ---------------------------------------------------------------------------
__global__ __launch_bounds__(256)
void zero2(float* __restrict__ a, int na, float* __restrict__ b, int nb) {
    const int i = blockIdx.x * 256 + threadIdx.x;
    if (i < na) a[i] = 0.f;
    else if (i < na + nb) b[i - na] = 0.f;
}

// ---------------------------------------------------------------------------
// Cast both weight matrices (ipw: n4a float4s, opw: n4b) in one dispatch.
// ---------------------------------------------------------------------------
__global__ __launch_bounds__(256)
void cast_weights(const float* __restrict__ ina, __hip_bfloat16* __restrict__ outa,
                  int n4a, const float* __restrict__ inb,
                  __hip_bfloat16* __restrict__ outb, int n4b) {
    int i = blockIdx.x * 256 + threadIdx.x;
    const float* in;
    __hip_bfloat16* out;
    if (i < n4a) { in = ina; out = outa; }
    else if (i < n4a + n4b) { in = inb; out = outb; i -= n4a; }
    else return;
    const float4 v = *(const float4*)(in + (size_t)i * 4);
    __hip_bfloat16 h0 = __float2bfloat16(v.x), h1 = __float2bfloat16(v.y);
    __hip_bfloat16 h2 = __float2bfloat16(v.z), h3 = __float2bfloat16(v.w);
    ushort4 p;
    p.x = *(unsigned short*)&h0; p.y = *(unsigned short*)&h1;
    p.z = *(unsigned short*)&h2; p.w = *(unsigned short*)&h3;
    *(ushort4*)((unsigned short*)out + (size_t)i * 4) = p;
}

// ---------------------------------------------------------------------------
// Transpose B/C rows of xdbl_T into xbc[l][32]: col s = B_s, col 16+s = C_s.
// ---------------------------------------------------------------------------
__global__ __launch_bounds__(256)
void transpose_bc(const float* __restrict__ xdbl_T, float* __restrict__ xbc) {
    __shared__ float tile[32][33];
    const int t = threadIdx.x;
    const int l0 = blockIdx.x * 32;
    const int s = t >> 3, lc = (t & 7) << 2;
    const float4 v = *(const float4*)(xdbl_T + (size_t)(DTRANK + s) * L_SEQ + l0 + lc);
    tile[s][lc + 0] = v.x; tile[s][lc + 1] = v.y;
    tile[s][lc + 2] = v.z; tile[s][lc + 3] = v.w;
    __syncthreads();
    const int l = t >> 3, sc = (t & 7) << 2;
    float4 w;
    w.x = tile[sc + 0][l]; w.y = tile[sc + 1][l];
    w.z = tile[sc + 2][l]; w.w = tile[sc + 3][l];
    *(float4*)(xbc + (size_t)(l0 + l) * 32 + sc) = w;
}

// ---------------------------------------------------------------------------
// bf16 transpose: out[Cc][R] = in[R][Cc]^T. 64x64 tiles.
// ---------------------------------------------------------------------------
__global__ __launch_bounds__(256)
void transpose_bf16(const unsigned short* __restrict__ in,
                    unsigned short* __restrict__ out, int R, int Cc) {
    __shared__ unsigned short tile[64][65];
    const int t = threadIdx.x;
    const int r0 = blockIdx.y * 64, c0 = blockIdx.x * 64;
    const int tr = t >> 3, tc8 = (t & 7) << 3;
    #pragma unroll
    for (int i = 0; i < 2; ++i) {
        const int r = tr + i * 32;
        const ushort4 v0 = *(const ushort4*)(in + (size_t)(r0 + r) * Cc + c0 + tc8);
        const ushort4 v1 = *(const ushort4*)(in + (size_t)(r0 + r) * Cc + c0 + tc8 + 4);
        tile[r][tc8 + 0] = v0.x; tile[r][tc8 + 1] = v0.y;
        tile[r][tc8 + 2] = v0.z; tile[r][tc8 + 3] = v0.w;
        tile[r][tc8 + 4] = v1.x; tile[r][tc8 + 5] = v1.y;
        tile[r][tc8 + 6] = v1.z; tile[r][tc8 + 7] = v1.w;
    }
    __syncthreads();
    #pragma unroll
    for (int i = 0; i < 2; ++i) {
        const int r = tr + i * 32;
        ushort4 w0, w1;
        w0.x = tile[tc8 + 0][r]; w0.y = tile[tc8 + 1][r];
        w0.z = tile[tc8 + 2][r]; w0.w = tile[tc8 + 3][r];
        w1.x = tile[tc8 + 4][r]; w1.y = tile[tc8 + 5][r];
        w1.z = tile[tc8 + 6][r]; w1.w = tile[tc8 + 7][r];
        *(ushort4*)(out + (size_t)(c0 + r) * R + r0 + tc8)     = w0;
        *(ushort4*)(out + (size_t)(c0 + r) * R + r0 + tc8 + 4) = w1;
    }
}

// ---------------------------------------------------------------------------
// Residual add + LayerNorm -> bf16. One block per row l.
// ---------------------------------------------------------------------------
__global__ __launch_bounds__(256)
void add_ln(const float* __restrict__ h, float* __restrict__ res,
            __hip_bfloat16* __restrict__ hn, const float* __restrict__ w,
            const float* __restrict__ b, int is_first) {
    const int l = blockIdx.x;
    const int t = threadIdx.x;
    float v[4];
    float s = 0.f, ss = 0.f;
    #pragma unroll
    for (int j = 0; j < 4; ++j) {
        const int d = t + j * 256;
        float x = h[(size_t)l * DMODEL + d];
        if (!is_first) x += res[(size_t)l * DMODEL + d];
        res[(size_t)l * DMODEL + d] = x;
        v[j] = x; s += x; ss += x * x;
    }
    #pragma unroll
    for (int o = 32; o > 0; o >>= 1) {
        s  += __shfl_down(s, o);
        ss += __shfl_down(ss, o);
    }
    __shared__ float sm[4], sm2[4];
    const int wid = t >> 6;
    if ((t & 63) == 0) { sm[wid] = s; sm2[wid] = ss; }
    __syncthreads();
    s  = sm[0] + sm[1] + sm[2] + sm[3];
    ss = sm2[0] + sm2[1] + sm2[2] + sm2[3];
    const float mu  = s * (1.f / DMODEL);
    const float var = ss * (1.f / DMODEL) - mu * mu;
    const float r   = rsqrtf(var + LN_EPS);
    #pragma unroll
    for (int j = 0; j < 4; ++j) {
        const int d = t + j * 256;
        hn[(size_t)l * DMODEL + d] = __float2bfloat16((v[j] - mu) * r * w[d] + b[d]);
    }
}

// ---------------------------------------------------------------------------
// Depthwise causal conv + bias + SiLU, transposed layout. Block = channel d.
// ---------------------------------------------------------------------------
__global__ __launch_bounds__(256)
void conv_silu_t(const float* __restrict__ xz_T, float* __restrict__ xc_T,
                 const float* __restrict__ cw, const float* __restrict__ cb) {
    const int d = blockIdx.x;
    const int t = threadIdx.x;
    __shared__ float row[L_SEQ];
    *(float4*)&row[t << 2] = *(const float4*)(xz_T + (size_t)d * L_SEQ + (t << 2));
    __syncthreads();
    const float w0 = cw[d * 4 + 0], w1 = cw[d * 4 + 1];
    const float w2 = cw[d * 4 + 2], w3 = cw[d * 4 + 3];
    const float bb = cb[d];
    float o[4];
    #pragma unroll
    for (int j = 0; j < 4; ++j) {
        const int l = (t << 2) + j;
        float acc = bb + w3 * row[l];
        if (l >= 1) acc += w2 * row[l - 1];
        if (l >= 2) acc += w1 * row[l - 2];
        if (l >= 3) acc += w0 * row[l - 3];
        const float sig = 1.f / (1.f + __expf(-acc));
        o[j] = acc * sig;
    }
    *(float4*)(xc_T + (size_t)d * L_SEQ + (t << 2)) = make_float4(o[0], o[1], o[2], o[3]);
}

// ---------------------------------------------------------------------------
// Chunk-parallel selective scan (R5 structure: 512 thr, CHUNK=32).
// Block = channel d. delta/xc/z staged in LDS (skewed); B/C from xbc[l][32].
// ---------------------------------------------------------------------------
__global__ __launch_bounds__(512)
void ssm_scan_t(const float* __restrict__ delta_T,
                const float* __restrict__ xc_T,
                const float* __restrict__ xbc,
                const float* __restrict__ xz_T,
                const float* __restrict__ alog,
                const float* __restrict__ dsk,
                __hip_bfloat16* __restrict__ y_T) {
    const int d = blockIdx.x;
    const int t = threadIdx.x;
    const int s = t & 15;
    const int c = t >> 4;

    __shared__ float sdl[L_SEQ + 32], sxl[L_SEQ + 32];
    __shared__ float sz[L_SEQ], sy[L_SEQ];
    __shared__ float saprod[NCHUNK][DSTATE];
    __shared__ float shloc[NCHUNK][DSTATE];
    __shared__ float shstart[NCHUNK][DSTATE];

    if (t < 256) {
        const float4 v = ((const float4*)(delta_T + (size_t)d * L_SEQ))[t];
        const int l = t << 2;
        sdl[SK(l)] = v.x; sdl[SK(l + 1)] = v.y;
        sdl[SK(l + 2)] = v.z; sdl[SK(l + 3)] = v.w;
        ((float4*)sz)[t] = ((const float4*)(xz_T + (size_t)(DINNER + d) * L_SEQ))[t];
    } else {
        const int tt = t - 256;
        const float4 v = ((const float4*)(xc_T + (size_t)d * L_SEQ))[tt];
        const int l = tt << 2;
        sxl[SK(l)] = v.x; sxl[SK(l + 1)] = v.y;
        sxl[SK(l + 2)] = v.z; sxl[SK(l + 3)] = v.w;
    }
    __syncthreads();

    const float A  = -expf(alog[d * DSTATE + s]);
    const int   l0 = c * CHUNK;

    // Phase 1: local scan, h0 = 0.
    float aprod = 1.f, h = 0.f;
    #pragma unroll 4
    for (int j = 0; j < CHUNK; ++j) {
        const int l = l0 + j;
        const float dl = sdl[SK(l)];
        const float da = __expf(dl * A);
        h = da * h + dl * xbc[(size_t)l * 32 + s] * sxl[SK(l)];
        aprod *= da;
    }
    saprod[c][s] = aprod;
    shloc[c][s]  = h;
    __syncthreads();

    // Phase 2: serial combine across 32 chunk summaries.
    if (c == 0) {
        float hs = 0.f;
        for (int cc = 0; cc < NCHUNK; ++cc) {
            shstart[cc][s] = hs;
            hs = saprod[cc][s] * hs + shloc[cc][s];
        }
    }
    __syncthreads();

    // Phase 3: rescan with true entry state, produce y.
    h = shstart[c][s];
    const float Dk = dsk[d];
    #pragma unroll 4
    for (int j = 0; j < CHUNK; ++j) {
        const int l = l0 + j;
        const float dl = sdl[SK(l)];
        const float xl = sxl[SK(l)];
        h = __expf(dl * A) * h + dl * xbc[(size_t)l * 32 + s] * xl;
        float cch = h * xbc[(size_t)l * 32 + 16 + s];
        cch += __shfl_xor(cch, 1, 16);
        cch += __shfl_xor(cch, 2, 16);
        cch += __shfl_xor(cch, 4, 16);
        cch += __shfl_xor(cch, 8, 16);
        if (s == 0) {
            const float zl  = sz[l];
            const float sig = 1.f / (1.f + __expf(-zl));
            sy[l] = (cch + xl * Dk) * (zl * sig);
        }
    }
    __syncthreads();

    if (t < 256) {
        const float4 v = ((const float4*)sy)[t];
        __hip_bfloat16 h0 = __float2bfloat16(v.x), h1 = __float2bfloat16(v.y);
        __hip_bfloat16 h2 = __float2bfloat16(v.z), h3 = __float2bfloat16(v.w);
        ushort4 p;
        p.x = *(unsigned short*)&h0; p.y = *(unsigned short*)&h1;
        p.z = *(unsigned short*)&h2; p.w = *(unsigned short*)&h3;
        *(ushort4*)((unsigned short*)y_T + (size_t)d * L_SEQ + (t << 2)) = p;
    }
}

// ---------------------------------------------------------------------------
extern "C" void kernel_launch(void* const* d_in, const int* in_sizes, int n_in,
                              void* d_out, int out_size, void* d_ws, size_t ws_size,
                              hipStream_t stream) {
    const float* input   = (const float*)d_in[0];
    const float* input_w = (const float*)d_in[2];
    const float* norm_w  = (const float*)d_in[3];
    const float* norm_b  = (const float*)d_in[4];
    const float* ipw     = (const float*)d_in[5];
    const float* cw      = (const float*)d_in[6];
    const float* cb      = (const float*)d_in[7];
    const float* xpw     = (const float*)d_in[8];
    const float* dtw     = (const float*)d_in[9];
    const float* dtb     = (const float*)d_in[10];
    const float* alog    = (const float*)d_in[11];
    const float* dsk     = (const float*)d_in[12];
    const float* opw     = (const float*)d_in[13];
    float* out = (float*)d_out;

    float* ws      = (float*)d_ws;
    float* h       = ws;                        // 1M floats
    float* res     = h       + (1u << 20);      // 1M
    float* xz_T    = res     + (1u << 20);      // 4M   [e][l]
    float* xc_T    = xz_T    + (4u << 20);      // 2M   [d][l]
    float* xdbl_T  = xc_T    + (2u << 20);      // 96*1024  [e][l]
    float* xbc     = xdbl_T  + (NXP * L_SEQ);   // 1024*32  [l][32]
    float* delta_T = xbc     + (L_SEQ * 32);    // 2M   [d][l]
    __hip_bfloat16* hn_bf  = (__hip_bfloat16*)(delta_T + (2u << 20));  // 1M halfs
    __hip_bfloat16* yT_bf  = hn_bf  + (1u << 20);                      // 2M halfs
    __hip_bfloat16* y_bf   = yT_bf  + (2u << 20);                      // 2M halfs
    __hip_bfloat16* ipw_bf = y_bf   + (2u << 20);                      // 4M halfs
    __hip_bfloat16* opw_bf = ipw_bf + (4u << 20);                      // 2M halfs

    const dim3 blk(256);
    const int n4_ipw = 2 * DINNER * DMODEL / 4;   // 1,048,576
    const int n4_opw = DMODEL * DINNER / 4;       //   524,288

    // h = input @ input_w^T   (runs once, fp32)
    gemm_nt<<<dim3(DMODEL / 64, L_SEQ / 64), blk, 0, stream>>>(
        input, input_w, h, L_SEQ, DMODEL, 512, 512, 512, DMODEL);

    for (int i = 0; i < 4; ++i) {
        // both weight casts in one dispatch
        cast_weights<<<(n4_ipw + n4_opw + 255) / 256, blk, 0, stream>>>(
            ipw + (size_t)i * 2 * DINNER * DMODEL, ipw_bf, n4_ipw,
            opw + (size_t)i * DMODEL * DINNER, opw_bf, n4_opw);

        add_ln<<<L_SEQ, 256, 0, stream>>>(
            h, res, hn_bf, norm_w + i * DMODEL, norm_b + i * DMODEL, i == 0);

        // zero xdbl_T (for splitk) + dst (for out_proj sk) in one dispatch;
        // dst=h is safe to zero now: add_ln already consumed it.
        float* dst = (i == 3) ? out : h;
        zero2<<<(NXP * L_SEQ + L_SEQ * DMODEL + 255) / 256, blk, 0, stream>>>(
            xdbl_T, NXP * L_SEQ, dst, L_SEQ * DMODEL);

        // xz_T[e][l] = ipw @ hn^T   (M=4096, N=1024, K=1024) bf16 MFMA
        gemm_bt_bf16<<<dim3(L_SEQ / 128, 2 * DINNER / 128), blk, 0, stream>>>(
            ipw_bf, hn_bf, xz_T, DMODEL, DMODEL, DMODEL, L_SEQ);

        // xc_T[d][l] = silu(conv(x) + cb)
        conv_silu_t<<<DINNER, 256, 0, stream>>>(
            xz_T, xc_T, cw + i * DINNER * 4, cb + i * DINNER);

        // xdbl_T[e][l] = xpw @ xc_T   (M=96, N=1024, K=2048) fp32 split-K
        gemm_nn_splitk<<<dim3(L_SEQ / 64, 3, 8), blk, 0, stream>>>(
            xpw + (size_t)i * NXP * DINNER, xc_T, xdbl_T,
            DINNER, L_SEQ, L_SEQ, DINNER / 8);

        // xbc[l][32] = (B|C) in line-friendly layout
        transpose_bc<<<L_SEQ / 32, 256, 0, stream>>>(xdbl_T, xbc);

        // delta_T[d][l] = softplus(dtw @ xdbl_T[:64] + dtb)
        gemm_nn_softplus<<<dim3(L_SEQ / 64, DINNER / 64), blk, 0, stream>>>(
            dtw + (size_t)i * DINNER * DTRANK, xdbl_T, dtb + i * DINNER, delta_T,
            DTRANK, DTRANK, L_SEQ, L_SEQ);

        ssm_scan_t<<<DINNER, 512, 0, stream>>>(
            delta_T, xc_T, xbc, xz_T,
            alog + i * DINNER * DSTATE, dsk + i * DINNER, yT_bf);

        // y_bf[l][d] = yT_bf^T
        transpose_bf16<<<dim3(L_SEQ / 64, DINNER / 64), blk, 0, stream>>>(
            (const unsigned short*)yT_bf, (unsigned short*)y_bf, DINNER, L_SEQ);

        // out = y @ opw^T   (M=1024, N=1024, K=2048) bf16 MFMA split-K x4
        gemm_bt_bf16_sk<<<dim3(DMODEL / 128, L_SEQ / 128, 4), blk, 0, stream>>>(
            y_bf, opw_bf, dst, DINNER / 4, DINNER, DINNER, DMODEL);
    }
}